// Round 7
// baseline (251.456 us; speedup 1.0000x reference)
//
#include <hip/hip_runtime.h>
#include <hip/hip_fp16.h>
#include <stdint.h>

typedef unsigned int u32;
typedef unsigned long long u64;
typedef unsigned short ushort_t;

// Problem constants
#define B_ 8
#define C_ 256
#define L_ 2048
#define K_ 8192
#define M_ 16384   // B_*L_

// ---- workspace layout (bytes) ----  (WS_NEED = 25460992, proven to fit)
#define WS_KEYS   0            // u64[16384] -> 131072
#define WS_CNT    131072       // u32
#define WS_MAXCS  131076       // u32 (float bits, positive -> int cmp ok)
#define WS_LOSS   131080       // f32
#define WS_XSQ    131328       // f32[16384] -> 196864
#define WS_CSQ    196864       // f32[8192]  -> 229632
#define WS_LIST   295168       // u32[1M]    -> 4489472
#define WS_LMAX   4489472      // fp16[16384*256] -> 12878080
#define WS_XTH    12878080     // bf16[16384*256] -> 21266688
#define WS_CBH    21266688     // bf16[8192*256]  -> 25460992
#define LIST_CAP  1048576u

typedef __attribute__((ext_vector_type(8))) short s8v;   // 8 x bf16 (4 VGPR)
typedef __attribute__((ext_vector_type(4))) float f4v;

__device__ __forceinline__ ushort_t f2bf(float f) {
  u32 u = __float_as_uint(f);
  u32 r = (u + 0x7FFFu + ((u >> 16) & 1u)) >> 16;   // RN-even
  return (ushort_t)r;
}

__device__ __forceinline__ void gld16(void* lds, const void* g) {
  __builtin_amdgcn_global_load_lds(
      (const __attribute__((address_space(1))) u32*)g,
      (__attribute__((address_space(3))) u32*)lds, 16, 0, 0);
}

// ---------------- prep kernels ----------------

// transpose x (B,C,L) -> xt fp32 (M,C) [into emb out region] + bf16 (M,C) [ws]
__global__ void __launch_bounds__(256)
vq_transpose(const float* __restrict__ x, float* __restrict__ xtf,
             ushort_t* __restrict__ xth) {
  __shared__ float t[64][65];
  int tid = threadIdx.x;
  int b  = blockIdx.x >> 7;
  int cc = (blockIdx.x >> 5) & 3;
  int lc = blockIdx.x & 31;
#pragma unroll
  for (int j = 0; j < 4; ++j) {
    int c  = (tid >> 4) + j * 16;
    int lq = tid & 15;
    float4 v = *(const float4*)&x[((size_t)(b * C_ + cc * 64 + c)) * L_ + lc * 64 + lq * 4];
    t[c][lq * 4 + 0] = v.x; t[c][lq * 4 + 1] = v.y;
    t[c][lq * 4 + 2] = v.z; t[c][lq * 4 + 3] = v.w;
  }
  __syncthreads();
  int l = tid >> 2, qc = tid & 3;
  size_t m = (size_t)b * L_ + lc * 64 + l;
#pragma unroll
  for (int j = 0; j < 4; ++j) {
    int q = qc + j * 4;                    // float4 index 0..15
    float4 v = make_float4(t[q * 4 + 0][l], t[q * 4 + 1][l],
                           t[q * 4 + 2][l], t[q * 4 + 3][l]);
    *(float4*)&xtf[m * C_ + cc * 64 + q * 4] = v;
    ushort4 h;
    h.x = f2bf(v.x); h.y = f2bf(v.y); h.z = f2bf(v.z); h.w = f2bf(v.w);
    *(ushort4*)&xth[m * C_ + cc * 64 + q * 4] = h;
  }
}

// xsq from transposed fp32 rows (coalesced, deterministic order)
__global__ void vq_xsqt(const float* __restrict__ xtf, float* __restrict__ xsq) {
  int t = threadIdx.x;
  int m = blockIdx.x * 16 + (t >> 4);              // 1024 blocks
  int g = t & 15;
  const float* row = xtf + (size_t)m * C_;
  float s = 0.0f;
#pragma unroll
  for (int j = 0; j < 4; ++j) {
    float4 v = *(const float4*)&row[g * 4 + j * 64];
    s += v.x * v.x + v.y * v.y + v.z * v.z + v.w * v.w;
  }
#pragma unroll
  for (int off = 1; off < 16; off <<= 1) s += __shfl_xor(s, off, 64);
  if (g == 0) xsq[m] = s;
}

// codebook: csq + maxcs + bf16 convert, one read of cb
__global__ void vq_cbprep(const float* __restrict__ cb, float* __restrict__ csq,
                          int* __restrict__ maxcs, ushort_t* __restrict__ cbh) {
  int t = threadIdx.x;
  int k = blockIdx.x * 16 + (t >> 4);              // 512 blocks
  int g = t & 15;
  const float* row = cb + (size_t)k * C_;
  float s = 0.0f;
#pragma unroll
  for (int j = 0; j < 4; ++j) {
    float4 v = *(const float4*)&row[g * 4 + j * 64];
    s += v.x * v.x + v.y * v.y + v.z * v.z + v.w * v.w;
    ushort4 h;
    h.x = f2bf(v.x); h.y = f2bf(v.y); h.z = f2bf(v.z); h.w = f2bf(v.w);
    *(ushort4*)&cbh[(size_t)k * C_ + g * 4 + j * 64] = h;
  }
#pragma unroll
  for (int off = 1; off < 16; off <<= 1) s += __shfl_xor(s, off, 64);
  if (g == 0) {
    csq[k] = s;
    atomicMax(maxcs, __float_as_int(s));   // positive floats: int cmp == float cmp
  }
}

// ---------------- single-pass MFMA GEMM, A in registers ----------------
// Round 7: (a) SWAPPED-OPERAND MFMA — mfma(codes, x) puts codes on the C-row
// axis, so per-32-code-block max is 7 in-register fmax + 2 shuffles (was a
// 4-level 16-lane shuffle reduce: 128 ds-swizzles/tile -> 16). (b) half-K
// staging: 128 codes x 128 k = 32KB tile, dbuf 64KB -> 2 blocks/CU.
// Grid 512 = 64 row-strips x 8 n-splits. Wave w: rows r0..r0+31 (A in 64 VGPR),
// all 128 codes of each tile. 16 stages (8 tiles x 2 K-halves).
// LDS layout: row = 128 bf16 = 16 chunks of 16B; chunk stored at
// sc = c ^ (row&7)  => read bank-group (c^(lr&7))&7 distinct over 8 lanes.

#define STAGE(buf, s_)                                                        \
  {                                                                           \
    const int t_ = (s_) >> 1, kh_ = (s_) & 1;                                 \
    _Pragma("unroll")                                                         \
    for (int q = 0; q < 4; ++q) {                                             \
      int chunk = (q * 8 + w) * 64 + l;      /* 0..2047, lane-linear */       \
      int row = chunk >> 4;                  /* 0..127 */                     \
      int csrc = lr ^ (row & 7);                                              \
      gld16(&Bs[(buf)][chunk * 8],                                            \
            &cbh[(size_t)(n0 + t_ * 128 + row) * 256 + kh_ * 128 + csrc * 8]);\
    }                                                                         \
  }

__global__ void __launch_bounds__(512, 2)
vq_gemm(const ushort_t* __restrict__ xth, const ushort_t* __restrict__ cbh,
        const float* __restrict__ csq, __half* __restrict__ lmax) {
  __shared__ short Bs[2][128 * 128];   // 2 x 32 KB

  const int tid = threadIdx.x;
  const int w = tid >> 6, l = tid & 63;
  const int lr = l & 15, lk = l >> 4;
  const int strip = blockIdx.x >> 3, ns = blockIdx.x & 7;
  const int r0 = strip * 256 + w * 32;
  const int n0 = ns * 1024;

  // A fragments: a[i][ksg] = row (r0+i*16+lr), k = ksg*32 + lk*8 .. +7
  s8v a[2][8];
#pragma unroll
  for (int i = 0; i < 2; ++i)
#pragma unroll
    for (int ks = 0; ks < 8; ++ks)
      a[i][ks] = *(const s8v*)&xth[(size_t)(r0 + i * 16 + lr) * 256 + ks * 32 + lk * 8];

  f4v acc[2][8];
  STAGE(0, 0);
  __syncthreads();

  for (int s = 0; s < 16; ++s) {
    const int buf = s & 1;
    const int kh = s & 1, tt = s >> 1;
    if (s < 15) STAGE(buf ^ 1, s + 1);   // issue next-stage loads BEFORE compute

    if (kh == 0) {
#pragma unroll
      for (int i = 0; i < 2; ++i)
#pragma unroll
        for (int j = 0; j < 8; ++j) acc[i][j] = (f4v){0.f, 0.f, 0.f, 0.f};
    }

#pragma unroll
    for (int ks = 0; ks < 4; ++ks) {
      s8v b[8];
#pragma unroll
      for (int j = 0; j < 8; ++j)
        b[j] = *(const s8v*)&Bs[buf][(j * 16 + lr) * 128 + (((ks * 4 + lk) ^ (lr & 7)) * 8)];
      // SWAPPED operands: D[code][xrow] — lane holds codes j*16+lk*4+r, xrow i*16+lr
#pragma unroll
      for (int i = 0; i < 2; ++i)
#pragma unroll
        for (int j = 0; j < 8; ++j)
          acc[i][j] = __builtin_amdgcn_mfma_f32_16x16x32_bf16(b[j], a[i][kh * 4 + ks], acc[i][j], 0, 0, 0);
    }

    if (kh == 1) {
      // epilogue: v = csq - 2*dot; per-lane max over 8 codes of each 32-block,
      // then 2-level shuffle over lk. Only 16 swizzles/tile.
      float vm[2][4];
#pragma unroll
      for (int jp = 0; jp < 4; ++jp) {
        float4 cqa = *(const float4*)&csq[n0 + tt * 128 + jp * 32 + lk * 4];
        float4 cqb = *(const float4*)&csq[n0 + tt * 128 + jp * 32 + 16 + lk * 4];
#pragma unroll
        for (int i = 0; i < 2; ++i) {
          f4v A0 = acc[i][2 * jp], A1 = acc[i][2 * jp + 1];
          float m0 = fmaxf(fmaxf(__fmaf_rn(-2.0f, A0[0], cqa.x),
                                 __fmaf_rn(-2.0f, A0[1], cqa.y)),
                           fmaxf(__fmaf_rn(-2.0f, A0[2], cqa.z),
                                 __fmaf_rn(-2.0f, A0[3], cqa.w)));
          float m1 = fmaxf(fmaxf(__fmaf_rn(-2.0f, A1[0], cqb.x),
                                 __fmaf_rn(-2.0f, A1[1], cqb.y)),
                           fmaxf(__fmaf_rn(-2.0f, A1[2], cqb.z),
                                 __fmaf_rn(-2.0f, A1[3], cqb.w)));
          float vmx = fmaxf(m0, m1);
          vmx = fmaxf(vmx, __shfl_xor(vmx, 16, 64));
          vmx = fmaxf(vmx, __shfl_xor(vmx, 32, 64));
          vm[i][jp] = vmx;
        }
      }
      if (l < 16) {
#pragma unroll
        for (int i = 0; i < 2; ++i) {
          short4 sv;
          sv.x = (short)__half_as_ushort(__float2half(vm[i][0]));
          sv.y = (short)__half_as_ushort(__float2half(vm[i][1]));
          sv.z = (short)__half_as_ushort(__float2half(vm[i][2]));
          sv.w = (short)__half_as_ushort(__float2half(vm[i][3]));
          *(short4*)&lmax[(size_t)(r0 + i * 16 + l) * 256 + ns * 32 + tt * 4] = sv;
        }
      }
    }
    __syncthreads();   // reads of Bs[buf] done; STAGE(s+1) drained (vmcnt 0 at barrier)
  }
}

// per-row threshold + candidate list, block-aggregated (one global atomic per
// block; entries at deterministic ballot-prefix positions).
__global__ void __launch_bounds__(256)
vq_thr(const __half* __restrict__ lmax, const float* __restrict__ xsq,
       const int* __restrict__ maxcs, u32* __restrict__ list, u32* __restrict__ cnt) {
  __shared__ u32 wcnt[4];
  __shared__ u32 gbase_s;
  const int t = threadIdx.x, w = t >> 6, l = t & 63;
  const int m0 = blockIdx.x * 64 + w * 16;
  const float mc = __int_as_float(*maxcs);

  ushort4 hv[16];
  float thv[16];
  u32 wtot = 0;
  // pass 1: load row, wave-max, threshold, count qualifiers
#pragma unroll
  for (int i = 0; i < 16; ++i) {
    int m = m0 + i;
    hv[i] = *(const ushort4*)&lmax[(size_t)m * 256 + l * 4];
    float v0 = __half2float(__ushort_as_half(hv[i].x));
    float v1 = __half2float(__ushort_as_half(hv[i].y));
    float v2 = __half2float(__ushort_as_half(hv[i].z));
    float v3 = __half2float(__ushort_as_half(hv[i].w));
    float g = fmaxf(fmaxf(v0, v1), fmaxf(v2, v3));
#pragma unroll
    for (int off = 1; off < 64; off <<= 1) g = fmaxf(g, __shfl_xor(g, off, 64));
    // rigorous margin: 2*(bf16 dot err bound 2*2^-7*sqrt(xsq*csq)) + fp16 slack
    float th = g - (0.033f * sqrtf(xsq[m] * mc) + 0.6f);
    thv[i] = th;
    wtot += __popcll(__ballot(v0 >= th));
    wtot += __popcll(__ballot(v1 >= th));
    wtot += __popcll(__ballot(v2 >= th));
    wtot += __popcll(__ballot(v3 >= th));
  }
  if (l == 0) wcnt[w] = wtot;
  __syncthreads();
  if (t == 0) gbase_s = atomicAdd(cnt, wcnt[0] + wcnt[1] + wcnt[2] + wcnt[3]);
  __syncthreads();
  u32 off = gbase_s;
  for (int ww = 0; ww < w; ++ww) off += wcnt[ww];
  // pass 2: write entries at deterministic ballot-prefix positions
#pragma unroll
  for (int i = 0; i < 16; ++i) {
    int m = m0 + i;
    float th = thv[i];
    float v[4];
    v[0] = __half2float(__ushort_as_half(hv[i].x));
    v[1] = __half2float(__ushort_as_half(hv[i].y));
    v[2] = __half2float(__ushort_as_half(hv[i].z));
    v[3] = __half2float(__ushort_as_half(hv[i].w));
#pragma unroll
    for (int j = 0; j < 4; ++j) {
      u64 mask = __ballot(v[j] >= th);
      if (v[j] >= th) {
        u32 pos = off + (u32)__popcll(mask & ((1ull << l) - 1ull));
        if (pos < LIST_CAP) list[pos] = ((u32)m << 8) | (u32)(l * 4 + j);
      }
      off += (u32)__popcll(mask);
    }
  }
}

// exact fp32 rescore of qualifying 32-code blocks; one wave per entry.
// 8 lanes per code x 8 codes in parallel. Mirrors numpy op order incl. sqrt;
// key packs (dist_bits, ~k) => first-max-wins.
__global__ void __launch_bounds__(256)
vq_rescore(const u32* __restrict__ list, const u32* __restrict__ cnt,
           const float* __restrict__ xtf, const float* __restrict__ cb,
           const float* __restrict__ xsq, const float* __restrict__ csq,
           u64* __restrict__ keys) {
  u32 n = *cnt; if (n > LIST_CAP) n = LIST_CAP;
  const int l = threadIdx.x & 63;
  const int u = l & 7;          // lane within 8-lane group
  const int g = l >> 3;         // group 0..7 (one code each)
  int wid = (blockIdx.x * 256 + threadIdx.x) >> 6;
  int nw = (gridDim.x * 256) >> 6;
  for (u32 e = wid; e < n; e += nw) {
    u32 ent = list[e];
    int m = (int)(ent >> 8), blk = (int)(ent & 255u);
    // preload x row chunks for this lane (elements (i*8+u)*4 .. +3)
    float4 xv[8];
#pragma unroll
    for (int i = 0; i < 8; ++i)
      xv[i] = *(const float4*)&xtf[(size_t)m * C_ + (i * 8 + u) * 4];
    float xq = xsq[m];
    u64 bestkey = 0;
#pragma unroll
    for (int cc = 0; cc < 4; ++cc) {
      int k = blk * 32 + cc * 8 + g;
      const float* crow = &cb[(size_t)k * C_];
      float p = 0.0f;
#pragma unroll
      for (int i = 0; i < 8; ++i) {
        float4 cv = *(const float4*)&crow[(i * 8 + u) * 4];
        p += xv[i].x * cv.x + xv[i].y * cv.y + xv[i].z * cv.z + xv[i].w * cv.w;
      }
#pragma unroll
      for (int off = 1; off < 8; off <<= 1) p += __shfl_xor(p, off, 64);
      if (u == 0) {
        // exact reference op order: (x_sq + c_sq) - 2*dot, clamp, sqrt
        float d2 = __fsub_rn(__fadd_rn(xq, csq[k]), __fmul_rn(2.0f, p));
        float dist = sqrtf(fmaxf(d2, 0.0f));
        u64 key = ((u64)__float_as_uint(dist) << 32) |
                  (u64)(0xFFFFFFFFu - (u32)k);
        if (key > bestkey) bestkey = key;   // max dist, tie -> smaller k
      }
    }
    // cross-group max (leaders hold keys; others hold 0)
#pragma unroll
    for (int off = 8; off < 64; off <<= 1) {
      u64 o = __shfl_xor(bestkey, off, 64);
      if (o > bestkey) bestkey = o;
    }
    if (l == 0) atomicMax(&keys[m], bestkey);
  }
}

// ---------------- outputs ----------------

// emb gather + loss partial + code output (folded round-7: saves a launch)
__global__ void __launch_bounds__(256)
vq_gather(const u64* __restrict__ keys, const float* __restrict__ cb,
          const float* __restrict__ x, float* __restrict__ out_code,
          float* __restrict__ emb, float* __restrict__ loss_acc) {
  __shared__ float rows[32 * 260];
  __shared__ int codes_s[32];
  __shared__ float partial[4];
  int t = threadIdx.x;
  int b = blockIdx.x >> 6;
  int l0 = (blockIdx.x & 63) * 32;
  if (t < 32) {
    u64 key = keys[b * L_ + l0 + t];
    int code = (int)(0xFFFFFFFFu - (u32)(key & 0xFFFFFFFFull));
    codes_s[t] = code;
    out_code[b * L_ + l0 + t] = (float)code;
  }
  __syncthreads();
  {
    int r = t >> 3, c4 = t & 7;
    const float* src = cb + (size_t)codes_s[r] * C_;
#pragma unroll
    for (int j = 0; j < 8; ++j) {
      float4 v = *(const float4*)&src[(c4 + 8 * j) * 4];
      *(float4*)&rows[r * 260 + (c4 + 8 * j) * 4] = v;
    }
  }
  __syncthreads();
  float ls = 0.0f;
  int l = t & 31, cg = t >> 5;
#pragma unroll 4
  for (int cs = 0; cs < 32; ++cs) {
    int c = cg * 32 + cs;
    float v = rows[l * 260 + c];
    size_t gi = (size_t)(b * C_ + c) * L_ + l0 + l;
    emb[gi] = v;
    float d = x[gi] - v;
    ls = fmaf(d, d, ls);
  }
#pragma unroll
  for (int off = 1; off < 64; off <<= 1) ls += __shfl_xor(ls, off, 64);
  if ((t & 63) == 0) partial[t >> 6] = ls;
  __syncthreads();
  if (t == 0)
    atomicAdd(loss_acc, partial[0] + partial[1] + partial[2] + partial[3]);
}

__global__ void vq_loss(const float* __restrict__ loss_acc, float* __restrict__ out) {
  out[0] = loss_acc[0] / 4194304.0f;
}

extern "C" void kernel_launch(void* const* d_in, const int* in_sizes, int n_in,
                              void* d_out, int out_size, void* d_ws, size_t ws_size,
                              hipStream_t stream) {
  const float* x  = (const float*)d_in[0];   // (8, 256, 2048)
  const float* cb = (const float*)d_in[1];   // (8192, 256)
  float* out = (float*)d_out;                // [code(16384) | emb(4194304) | loss(1)]
  char* ws = (char*)d_ws;

  u64* keys      = (u64*)(ws + WS_KEYS);
  u32* cnt       = (u32*)(ws + WS_CNT);
  int* maxcs     = (int*)(ws + WS_MAXCS);
  float* loss_a  = (float*)(ws + WS_LOSS);
  float* xsq     = (float*)(ws + WS_XSQ);
  float* csq     = (float*)(ws + WS_CSQ);
  u32* list      = (u32*)(ws + WS_LIST);
  __half* lmax   = (__half*)(ws + WS_LMAX);
  ushort_t* xth  = (ushort_t*)(ws + WS_XTH);
  ushort_t* cbh  = (ushort_t*)(ws + WS_CBH);
  float* xtf     = out + M_;                 // emb region doubles as fp32 x^T scratch

  hipMemsetAsync(ws, 0, 131084, stream);     // keys + cnt + maxcs + loss

  vq_transpose<<<1024, 256, 0, stream>>>(x, xtf, xth);
  vq_cbprep<<<K_ / 16, 256, 0, stream>>>(cb, csq, maxcs, cbh);
  vq_xsqt<<<M_ / 16, 256, 0, stream>>>(xtf, xsq);
  vq_gemm<<<512, 512, 0, stream>>>(xth, cbh, csq, lmax);
  vq_thr<<<256, 256, 0, stream>>>(lmax, xsq, maxcs, list, cnt);
  vq_rescore<<<2048, 256, 0, stream>>>(list, cnt, xtf, cb, xsq, csq, keys);
  vq_gather<<<(B_ * L_) / 32, 256, 0, stream>>>(keys, cb, x, out, out + M_, loss_a);
  vq_loss<<<1, 1, 0, stream>>>(loss_a, out + M_ + (size_t)B_ * C_ * L_);
}

// Round 8
// 248.336 us; speedup vs baseline: 1.0126x; 1.0126x over previous
//
#include <hip/hip_runtime.h>
#include <hip/hip_fp16.h>
#include <stdint.h>

typedef unsigned int u32;
typedef unsigned long long u64;
typedef unsigned short ushort_t;

// Problem constants
#define B_ 8
#define C_ 256
#define L_ 2048
#define K_ 8192
#define M_ 16384   // B_*L_

// ---- workspace layout (bytes) ----  (WS_NEED = 25460992, proven to fit)
#define WS_KEYS   0            // u64[16384] -> 131072
#define WS_CNT    131072       // u32
#define WS_MAXCS  131076       // u32 (float bits, positive -> int cmp ok)
#define WS_LOSS   131080       // f32
#define WS_XSQ    131328       // f32[16384] -> 196864
#define WS_CSQ    196864       // f32[8192]  -> 229632
#define WS_LIST   295168       // u32[1M]    -> 4489472
#define WS_LMAX   4489472      // fp16[16384*256] -> 12878080
#define WS_XTH    12878080     // bf16[16384*256] -> 21266688
#define WS_CBH    21266688     // bf16[8192*256]  -> 25460992
#define LIST_CAP  1048576u

typedef __attribute__((ext_vector_type(8))) short s8v;   // 8 x bf16 (4 VGPR)
typedef __attribute__((ext_vector_type(4))) float f4v;

__device__ __forceinline__ ushort_t f2bf(float f) {
  u32 u = __float_as_uint(f);
  u32 r = (u + 0x7FFFu + ((u >> 16) & 1u)) >> 16;   // RN-even
  return (ushort_t)r;
}

__device__ __forceinline__ void gld16(void* lds, const void* g) {
  __builtin_amdgcn_global_load_lds(
      (const __attribute__((address_space(1))) u32*)g,
      (__attribute__((address_space(3))) u32*)lds, 16, 0, 0);
}

// ---------------- prep kernels ----------------

// transpose x (B,C,L) -> xt fp32 (M,C) [into emb out region] + bf16 (M,C) [ws]
__global__ void __launch_bounds__(256)
vq_transpose(const float* __restrict__ x, float* __restrict__ xtf,
             ushort_t* __restrict__ xth) {
  __shared__ float t[64][65];
  int tid = threadIdx.x;
  int b  = blockIdx.x >> 7;
  int cc = (blockIdx.x >> 5) & 3;
  int lc = blockIdx.x & 31;
#pragma unroll
  for (int j = 0; j < 4; ++j) {
    int c  = (tid >> 4) + j * 16;
    int lq = tid & 15;
    float4 v = *(const float4*)&x[((size_t)(b * C_ + cc * 64 + c)) * L_ + lc * 64 + lq * 4];
    t[c][lq * 4 + 0] = v.x; t[c][lq * 4 + 1] = v.y;
    t[c][lq * 4 + 2] = v.z; t[c][lq * 4 + 3] = v.w;
  }
  __syncthreads();
  int l = tid >> 2, qc = tid & 3;
  size_t m = (size_t)b * L_ + lc * 64 + l;
#pragma unroll
  for (int j = 0; j < 4; ++j) {
    int q = qc + j * 4;                    // float4 index 0..15
    float4 v = make_float4(t[q * 4 + 0][l], t[q * 4 + 1][l],
                           t[q * 4 + 2][l], t[q * 4 + 3][l]);
    *(float4*)&xtf[m * C_ + cc * 64 + q * 4] = v;
    ushort4 h;
    h.x = f2bf(v.x); h.y = f2bf(v.y); h.z = f2bf(v.z); h.w = f2bf(v.w);
    *(ushort4*)&xth[m * C_ + cc * 64 + q * 4] = h;
  }
}

// xsq from transposed fp32 rows (coalesced, deterministic order)
__global__ void vq_xsqt(const float* __restrict__ xtf, float* __restrict__ xsq) {
  int t = threadIdx.x;
  int m = blockIdx.x * 16 + (t >> 4);              // 1024 blocks
  int g = t & 15;
  const float* row = xtf + (size_t)m * C_;
  float s = 0.0f;
#pragma unroll
  for (int j = 0; j < 4; ++j) {
    float4 v = *(const float4*)&row[g * 4 + j * 64];
    s += v.x * v.x + v.y * v.y + v.z * v.z + v.w * v.w;
  }
#pragma unroll
  for (int off = 1; off < 16; off <<= 1) s += __shfl_xor(s, off, 64);
  if (g == 0) xsq[m] = s;
}

// codebook: csq + maxcs + bf16 convert, one read of cb
__global__ void vq_cbprep(const float* __restrict__ cb, float* __restrict__ csq,
                          int* __restrict__ maxcs, ushort_t* __restrict__ cbh) {
  int t = threadIdx.x;
  int k = blockIdx.x * 16 + (t >> 4);              // 512 blocks
  int g = t & 15;
  const float* row = cb + (size_t)k * C_;
  float s = 0.0f;
#pragma unroll
  for (int j = 0; j < 4; ++j) {
    float4 v = *(const float4*)&row[g * 4 + j * 64];
    s += v.x * v.x + v.y * v.y + v.z * v.z + v.w * v.w;
    ushort4 h;
    h.x = f2bf(v.x); h.y = f2bf(v.y); h.z = f2bf(v.z); h.w = f2bf(v.w);
    *(ushort4*)&cbh[(size_t)k * C_ + g * 4 + j * 64] = h;
  }
#pragma unroll
  for (int off = 1; off < 16; off <<= 1) s += __shfl_xor(s, off, 64);
  if (g == 0) {
    csq[k] = s;
    atomicMax(maxcs, __float_as_int(s));   // positive floats: int cmp == float cmp
  }
}

// ---------------- single-pass MFMA GEMM, A in registers ----------------
// Round 8: round-6 memory shape (grid 256 = 64 strips x 4 n-splits, full-K
// 64KB tiles, dbuf 128KB, FETCH ~20MB proven) + round-7 swapped-operand
// epilogue + NEW 4x2 wave tiling: wave = 64 rows x 64 codes, so each B
// ds_read_b128 feeds 4 MFMAs (was 2) -> block LDS reads halve (8192->4096).
// Wave w: wr=w>>1 (row group, 64 rows), wc=w&1 (code half, 64 codes).
// lmax col = ns*64 + t*4 + wc*2 + jp  (col*32 == global code base, ordered).

#define STAGE(buf, t_)                                                        \
  {                                                                           \
    _Pragma("unroll")                                                         \
    for (int q = 0; q < 8; ++q) {                                             \
      int codeT = (w * 8 + q) * 2 + (l >> 5);                                 \
      int chunk = l & 31;                                                     \
      gld16(&Bs[(buf)][(w * 8 + q) * 512],                                    \
            &cbh[(size_t)(n0 + (t_) * 128 + codeT) * 256 +                    \
                 ((chunk ^ (codeT & 7)) * 8)]);                               \
    }                                                                         \
  }

__global__ void __launch_bounds__(512, 2)
vq_gemm(const ushort_t* __restrict__ xth, const ushort_t* __restrict__ cbh,
        const float* __restrict__ csq, __half* __restrict__ lmax) {
  __shared__ short Bs[2][128 * 256];   // 2 x 64 KB

  const int tid = threadIdx.x;
  const int w = tid >> 6, l = tid & 63;
  const int lr = l & 15, lk = l >> 4;
  const int wr = w >> 1, wc = w & 1;
  const int strip = blockIdx.x >> 2, ns = blockIdx.x & 3;
  const int r0 = strip * 256 + wr * 64;
  const int n0 = ns * 2048;

  // A fragments: a[i][ks] = row (r0+i*16+lr), k = ks*32 + lk*8 .. +7  (128 VGPR)
  s8v a[4][8];
#pragma unroll
  for (int i = 0; i < 4; ++i)
#pragma unroll
    for (int ks = 0; ks < 8; ++ks)
      a[i][ks] = *(const s8v*)&xth[(size_t)(r0 + i * 16 + lr) * 256 + ks * 32 + lk * 8];

  STAGE(0, 0);
  __syncthreads();

  for (int t = 0; t < 16; ++t) {
    const int buf = t & 1;
    if (t < 15) STAGE(buf ^ 1, t + 1);   // issue next-tile loads BEFORE compute

    f4v acc[4][4];
#pragma unroll
    for (int i = 0; i < 4; ++i)
#pragma unroll
      for (int j = 0; j < 4; ++j) acc[i][j] = (f4v){0.f, 0.f, 0.f, 0.f};

#pragma unroll
    for (int ks = 0; ks < 8; ++ks) {
      s8v b[4];
#pragma unroll
      for (int j = 0; j < 4; ++j) {
        int row = wc * 64 + j * 16 + lr;
        b[j] = *(const s8v*)&Bs[buf][row * 256 + (((ks * 4 + lk) ^ (lr & 7)) * 8)];
      }
      // SWAPPED operands: D[code][xrow] — lane holds codes lk*4+r, xrow = lr
#pragma unroll
      for (int i = 0; i < 4; ++i)
#pragma unroll
        for (int j = 0; j < 4; ++j)
          acc[i][j] = __builtin_amdgcn_mfma_f32_16x16x32_bf16(b[j], a[i][ks], acc[i][j], 0, 0, 0);
    }

    // epilogue: v = csq - 2*dot; per-lane max over 8 codes (2 j x 4 reg) of a
    // 32-code block, then 2 shuffles over lk. cbase = this wave's code base.
    const int cbase = n0 + t * 128 + wc * 64;
    float vm[4][2];
#pragma unroll
    for (int jp = 0; jp < 2; ++jp) {
      float4 cqa = *(const float4*)&csq[cbase + jp * 32 + lk * 4];
      float4 cqb = *(const float4*)&csq[cbase + jp * 32 + 16 + lk * 4];
#pragma unroll
      for (int i = 0; i < 4; ++i) {
        f4v A0 = acc[i][2 * jp], A1 = acc[i][2 * jp + 1];
        float m0 = fmaxf(fmaxf(__fmaf_rn(-2.0f, A0[0], cqa.x),
                               __fmaf_rn(-2.0f, A0[1], cqa.y)),
                         fmaxf(__fmaf_rn(-2.0f, A0[2], cqa.z),
                               __fmaf_rn(-2.0f, A0[3], cqa.w)));
        float m1 = fmaxf(fmaxf(__fmaf_rn(-2.0f, A1[0], cqb.x),
                               __fmaf_rn(-2.0f, A1[1], cqb.y)),
                         fmaxf(__fmaf_rn(-2.0f, A1[2], cqb.z),
                               __fmaf_rn(-2.0f, A1[3], cqb.w)));
        float vmx = fmaxf(m0, m1);
        vmx = fmaxf(vmx, __shfl_xor(vmx, 16, 64));
        vmx = fmaxf(vmx, __shfl_xor(vmx, 32, 64));
        vm[i][jp] = vmx;
      }
    }
    if (l < 16) {
#pragma unroll
      for (int i = 0; i < 4; ++i) {
        short2 sv;
        sv.x = (short)__half_as_ushort(__float2half(vm[i][0]));
        sv.y = (short)__half_as_ushort(__float2half(vm[i][1]));
        *(short2*)&lmax[(size_t)(r0 + i * 16 + l) * 256 + ns * 64 + t * 4 + wc * 2] = sv;
      }
    }
    __syncthreads();   // reads of Bs[buf] done; STAGE(t+1) drained (vmcnt 0 at barrier)
  }
}

// per-row threshold + candidate list, block-aggregated (one global atomic per
// block; entries at deterministic ballot-prefix positions).
__global__ void __launch_bounds__(256)
vq_thr(const __half* __restrict__ lmax, const float* __restrict__ xsq,
       const int* __restrict__ maxcs, u32* __restrict__ list, u32* __restrict__ cnt) {
  __shared__ u32 wcnt[4];
  __shared__ u32 gbase_s;
  const int t = threadIdx.x, w = t >> 6, l = t & 63;
  const int m0 = blockIdx.x * 64 + w * 16;
  const float mc = __int_as_float(*maxcs);

  ushort4 hv[16];
  float thv[16];
  u32 wtot = 0;
  // pass 1: load row, wave-max, threshold, count qualifiers
#pragma unroll
  for (int i = 0; i < 16; ++i) {
    int m = m0 + i;
    hv[i] = *(const ushort4*)&lmax[(size_t)m * 256 + l * 4];
    float v0 = __half2float(__ushort_as_half(hv[i].x));
    float v1 = __half2float(__ushort_as_half(hv[i].y));
    float v2 = __half2float(__ushort_as_half(hv[i].z));
    float v3 = __half2float(__ushort_as_half(hv[i].w));
    float g = fmaxf(fmaxf(v0, v1), fmaxf(v2, v3));
#pragma unroll
    for (int off = 1; off < 64; off <<= 1) g = fmaxf(g, __shfl_xor(g, off, 64));
    // rigorous margin: 2*(bf16 dot err bound 2*2^-7*sqrt(xsq*csq)) + fp16 slack
    float th = g - (0.033f * sqrtf(xsq[m] * mc) + 0.6f);
    thv[i] = th;
    wtot += __popcll(__ballot(v0 >= th));
    wtot += __popcll(__ballot(v1 >= th));
    wtot += __popcll(__ballot(v2 >= th));
    wtot += __popcll(__ballot(v3 >= th));
  }
  if (l == 0) wcnt[w] = wtot;
  __syncthreads();
  if (t == 0) gbase_s = atomicAdd(cnt, wcnt[0] + wcnt[1] + wcnt[2] + wcnt[3]);
  __syncthreads();
  u32 off = gbase_s;
  for (int ww = 0; ww < w; ++ww) off += wcnt[ww];
  // pass 2: write entries at deterministic ballot-prefix positions
#pragma unroll
  for (int i = 0; i < 16; ++i) {
    int m = m0 + i;
    float th = thv[i];
    float v[4];
    v[0] = __half2float(__ushort_as_half(hv[i].x));
    v[1] = __half2float(__ushort_as_half(hv[i].y));
    v[2] = __half2float(__ushort_as_half(hv[i].z));
    v[3] = __half2float(__ushort_as_half(hv[i].w));
#pragma unroll
    for (int j = 0; j < 4; ++j) {
      u64 mask = __ballot(v[j] >= th);
      if (v[j] >= th) {
        u32 pos = off + (u32)__popcll(mask & ((1ull << l) - 1ull));
        if (pos < LIST_CAP) list[pos] = ((u32)m << 8) | (u32)(l * 4 + j);
      }
      off += (u32)__popcll(mask);
    }
  }
}

// exact fp32 rescore of qualifying 32-code blocks; one wave per entry.
// 8 lanes per code x 8 codes in parallel. Mirrors numpy op order incl. sqrt;
// key packs (dist_bits, ~k) => first-max-wins.
__global__ void __launch_bounds__(256)
vq_rescore(const u32* __restrict__ list, const u32* __restrict__ cnt,
           const float* __restrict__ xtf, const float* __restrict__ cb,
           const float* __restrict__ xsq, const float* __restrict__ csq,
           u64* __restrict__ keys) {
  u32 n = *cnt; if (n > LIST_CAP) n = LIST_CAP;
  const int l = threadIdx.x & 63;
  const int u = l & 7;          // lane within 8-lane group
  const int g = l >> 3;         // group 0..7 (one code each)
  int wid = (blockIdx.x * 256 + threadIdx.x) >> 6;
  int nw = (gridDim.x * 256) >> 6;
  for (u32 e = wid; e < n; e += nw) {
    u32 ent = list[e];
    int m = (int)(ent >> 8), blk = (int)(ent & 255u);
    // preload x row chunks for this lane (elements (i*8+u)*4 .. +3)
    float4 xv[8];
#pragma unroll
    for (int i = 0; i < 8; ++i)
      xv[i] = *(const float4*)&xtf[(size_t)m * C_ + (i * 8 + u) * 4];
    float xq = xsq[m];
    u64 bestkey = 0;
#pragma unroll
    for (int cc = 0; cc < 4; ++cc) {
      int k = blk * 32 + cc * 8 + g;
      const float* crow = &cb[(size_t)k * C_];
      float p = 0.0f;
#pragma unroll
      for (int i = 0; i < 8; ++i) {
        float4 cv = *(const float4*)&crow[(i * 8 + u) * 4];
        p += xv[i].x * cv.x + xv[i].y * cv.y + xv[i].z * cv.z + xv[i].w * cv.w;
      }
#pragma unroll
      for (int off = 1; off < 8; off <<= 1) p += __shfl_xor(p, off, 64);
      if (u == 0) {
        // exact reference op order: (x_sq + c_sq) - 2*dot, clamp, sqrt
        float d2 = __fsub_rn(__fadd_rn(xq, csq[k]), __fmul_rn(2.0f, p));
        float dist = sqrtf(fmaxf(d2, 0.0f));
        u64 key = ((u64)__float_as_uint(dist) << 32) |
                  (u64)(0xFFFFFFFFu - (u32)k);
        if (key > bestkey) bestkey = key;   // max dist, tie -> smaller k
      }
    }
    // cross-group max (leaders hold keys; others hold 0)
#pragma unroll
    for (int off = 8; off < 64; off <<= 1) {
      u64 o = __shfl_xor(bestkey, off, 64);
      if (o > bestkey) bestkey = o;
    }
    if (l == 0) atomicMax(&keys[m], bestkey);
  }
}

// ---------------- outputs ----------------

// emb gather + loss partial + code output
__global__ void __launch_bounds__(256)
vq_gather(const u64* __restrict__ keys, const float* __restrict__ cb,
          const float* __restrict__ x, float* __restrict__ out_code,
          float* __restrict__ emb, float* __restrict__ loss_acc) {
  __shared__ float rows[32 * 260];
  __shared__ int codes_s[32];
  __shared__ float partial[4];
  int t = threadIdx.x;
  int b = blockIdx.x >> 6;
  int l0 = (blockIdx.x & 63) * 32;
  if (t < 32) {
    u64 key = keys[b * L_ + l0 + t];
    int code = (int)(0xFFFFFFFFu - (u32)(key & 0xFFFFFFFFull));
    codes_s[t] = code;
    out_code[b * L_ + l0 + t] = (float)code;
  }
  __syncthreads();
  {
    int r = t >> 3, c4 = t & 7;
    const float* src = cb + (size_t)codes_s[r] * C_;
#pragma unroll
    for (int j = 0; j < 8; ++j) {
      float4 v = *(const float4*)&src[(c4 + 8 * j) * 4];
      *(float4*)&rows[r * 260 + (c4 + 8 * j) * 4] = v;
    }
  }
  __syncthreads();
  float ls = 0.0f;
  int l = t & 31, cg = t >> 5;
#pragma unroll 4
  for (int cs = 0; cs < 32; ++cs) {
    int c = cg * 32 + cs;
    float v = rows[l * 260 + c];
    size_t gi = (size_t)(b * C_ + c) * L_ + l0 + l;
    emb[gi] = v;
    float d = x[gi] - v;
    ls = fmaf(d, d, ls);
  }
#pragma unroll
  for (int off = 1; off < 64; off <<= 1) ls += __shfl_xor(ls, off, 64);
  if ((t & 63) == 0) partial[t >> 6] = ls;
  __syncthreads();
  if (t == 0)
    atomicAdd(loss_acc, partial[0] + partial[1] + partial[2] + partial[3]);
}

__global__ void vq_loss(const float* __restrict__ loss_acc, float* __restrict__ out) {
  out[0] = loss_acc[0] / 4194304.0f;
}

extern "C" void kernel_launch(void* const* d_in, const int* in_sizes, int n_in,
                              void* d_out, int out_size, void* d_ws, size_t ws_size,
                              hipStream_t stream) {
  const float* x  = (const float*)d_in[0];   // (8, 256, 2048)
  const float* cb = (const float*)d_in[1];   // (8192, 256)
  float* out = (float*)d_out;                // [code(16384) | emb(4194304) | loss(1)]
  char* ws = (char*)d_ws;

  u64* keys      = (u64*)(ws + WS_KEYS);
  u32* cnt       = (u32*)(ws + WS_CNT);
  int* maxcs     = (int*)(ws + WS_MAXCS);
  float* loss_a  = (float*)(ws + WS_LOSS);
  float* xsq     = (float*)(ws + WS_XSQ);
  float* csq     = (float*)(ws + WS_CSQ);
  u32* list      = (u32*)(ws + WS_LIST);
  __half* lmax   = (__half*)(ws + WS_LMAX);
  ushort_t* xth  = (ushort_t*)(ws + WS_XTH);
  ushort_t* cbh  = (ushort_t*)(ws + WS_CBH);
  float* xtf     = out + M_;                 // emb region doubles as fp32 x^T scratch

  hipMemsetAsync(ws, 0, 131084, stream);     // keys + cnt + maxcs + loss

  vq_transpose<<<1024, 256, 0, stream>>>(x, xtf, xth);
  vq_cbprep<<<K_ / 16, 256, 0, stream>>>(cb, csq, maxcs, cbh);
  vq_xsqt<<<M_ / 16, 256, 0, stream>>>(xtf, xsq);
  vq_gemm<<<256, 512, 0, stream>>>(xth, cbh, csq, lmax);
  vq_thr<<<256, 256, 0, stream>>>(lmax, xsq, maxcs, list, cnt);
  vq_rescore<<<2048, 256, 0, stream>>>(list, cnt, xtf, cb, xsq, csq, keys);
  vq_gather<<<(B_ * L_) / 32, 256, 0, stream>>>(keys, cb, x, out, out + M_, loss_a);
  vq_loss<<<1, 1, 0, stream>>>(loss_a, out + M_ + (size_t)B_ * C_ * L_);
}